// Round 1
// baseline (3083.612 us; speedup 1.0000x reference)
//
#include <hip/hip_runtime.h>
#include <stdint.h>

// HeatDiffusion: out = rownorm( mask_topk16_sym(expm(-5*adj)) symmetrized + I )
// N=4096. expm via scaling-and-squaring: P = deg-4 Taylor of M=-5*adj/16, heat=P^16.
// fp32 GEMMs emulated as 3x bf16 MFMA (hi/lo split planes), m97-style kernel.
// Workspace layout: slotA (2 planes, 64MiB) | slotB (64MiB) | thr (16KB).
// d_out doubles as a third plane slot until the final kernel overwrites it.
// Requires ws_size >= 128MiB + 16KB.

#define NN 4096
#define BM 128
#define BN 128
#define BK 32

typedef unsigned short u16;
typedef __attribute__((ext_vector_type(8))) short short8;   // 8 bf16 = 4 VGPR
typedef __attribute__((ext_vector_type(4))) float f32x4;

__device__ __forceinline__ float bf2f(u16 u) {
  return __uint_as_float(((unsigned int)u) << 16);
}
__device__ __forceinline__ u16 f2bf(float f) {  // round-to-nearest-even
  unsigned int u = __float_as_uint(f);
  return (u16)((u + 0x7fffu + ((u >> 16) & 1u)) >> 16);
}

// async global->LDS, 16B per lane (global_load_lds_dwordx4). LDS dest must be
// wave-uniform base + lane*16 — our chunk mapping guarantees that.
__device__ __forceinline__ void async16(const void* g, void* l) {
  auto gp = reinterpret_cast<const __attribute__((address_space(1))) unsigned int*>(
      reinterpret_cast<uintptr_t>(g));
  auto lp = reinterpret_cast<__attribute__((address_space(3))) unsigned int*>(
      reinterpret_cast<uintptr_t>(l));
  __builtin_amdgcn_global_load_lds(gp, lp, 16, 0, 0);
}

// ---- split fp32 -> bf16 hi/lo planes, with scale -------------------------
extern "C" __global__ void __launch_bounds__(256) k_split_scale(
    const float* __restrict__ src, u16* __restrict__ h, u16* __restrict__ l,
    float s) {
  int i = blockIdx.x * 256 + threadIdx.x;           // over N*N/4
  float4 v = ((const float4*)src)[i];
  v.x *= s; v.y *= s; v.z *= s; v.w *= s;
  ushort4 hv, lv;
  u16 t;
  t = f2bf(v.x); hv.x = t; lv.x = f2bf(v.x - bf2f(t));
  t = f2bf(v.y); hv.y = t; lv.y = f2bf(v.y - bf2f(t));
  t = f2bf(v.z); hv.z = t; lv.z = f2bf(v.z - bf2f(t));
  t = f2bf(v.w); hv.w = t; lv.w = f2bf(v.w - bf2f(t));
  ((ushort4*)h)[i] = hv;
  ((ushort4*)l)[i] = lv;
}

// ---- Z = transpose(sx*X + sy*Y), planes in/out ---------------------------
extern "C" __global__ void __launch_bounds__(256) k_transpose_combine(
    const u16* __restrict__ Xh, const u16* __restrict__ Xl,
    const u16* __restrict__ Yh, const u16* __restrict__ Yl,
    u16* __restrict__ Zh, u16* __restrict__ Zl, float sx, float sy) {
  __shared__ float tile[64][65];
  const int tx = threadIdx.x & 63;
  const int ty = threadIdx.x >> 6;
  const int r0 = blockIdx.y * 64, c0 = blockIdx.x * 64;
  for (int r = ty; r < 64; r += 4) {
    size_t g = (size_t)(r0 + r) * NN + (c0 + tx);
    float v = sx * (bf2f(Xh[g]) + bf2f(Xl[g]));
    if (Yh) v += sy * (bf2f(Yh[g]) + bf2f(Yl[g]));
    tile[r][tx] = v;
  }
  __syncthreads();
  for (int r = ty; r < 64; r += 4) {
    size_t g = (size_t)(c0 + r) * NN + (r0 + tx);
    float v = tile[tx][r];
    u16 hh = f2bf(v);
    Zh[g] = hh;
    Zl[g] = f2bf(v - bf2f(hh));
  }
}

// ---- C = A*B (+ epi: e0*I + e1*X + e2*Y), all matrices as hi/lo planes ---
// A row-major planes; B passed TRANSPOSED (Bt = B^T row-major planes).
// 128x128 tile, BK=32, 4 waves, 4x4 mfma_f32_16x16x32_bf16 per wave,
// 3 MFMA per tile-pair (hh, hl, lh) into one fp32 accumulator.
extern "C" __global__ void __launch_bounds__(256, 2) k_gemm(
    const u16* __restrict__ Ah, const u16* __restrict__ Al,
    const u16* __restrict__ Bth, const u16* __restrict__ Btl,
    u16* __restrict__ Ch, u16* __restrict__ Cl,
    const u16* __restrict__ Xh, const u16* __restrict__ Xl,
    const u16* __restrict__ Yh, const u16* __restrict__ Yl,
    float e0, float e1, float e2) {
  __shared__ alignas(16) u16 sAh[BM * BK];
  __shared__ alignas(16) u16 sAl[BM * BK];
  __shared__ alignas(16) u16 sBh[BN * BK];
  __shared__ alignas(16) u16 sBl[BN * BK];

  const int tid  = threadIdx.x;
  const int lane = tid & 63;
  const int wave = tid >> 6;
  const int wr = wave >> 1, wc = wave & 1;   // wave's 64x64 quadrant
  const int quad = lane >> 4;
  const int lrow = lane & 15;
  const int m0 = blockIdx.x * BM;
  const int n0 = blockIdx.y * BN;

  f32x4 acc[4][4];
#pragma unroll
  for (int i = 0; i < 4; ++i)
#pragma unroll
    for (int j = 0; j < 4; ++j) acc[i][j] = (f32x4){0.f, 0.f, 0.f, 0.f};

  // staging: plane tile = 128x32 u16 = 8KB = 512 chunks of 16B; thread does
  // chunks tid and tid+256. chunk q -> row q>>2, cols (q&3)*8.., LDS elem q*8.
  const int q0 = tid, q1 = tid + 256;
  const int row0 = q0 >> 2, co0 = (q0 & 3) * 8;
  const int row1 = q1 >> 2, co1 = (q1 & 3) * 8;
  const size_t ga0 = (size_t)(m0 + row0) * NN + co0;
  const size_t ga1 = (size_t)(m0 + row1) * NN + co1;
  const size_t gb0 = (size_t)(n0 + row0) * NN + co0;
  const size_t gb1 = (size_t)(n0 + row1) * NN + co1;

  for (int k = 0; k < NN; k += BK) {
    async16(Ah + ga0 + k, &sAh[q0 * 8]);
    async16(Ah + ga1 + k, &sAh[q1 * 8]);
    async16(Al + ga0 + k, &sAl[q0 * 8]);
    async16(Al + ga1 + k, &sAl[q1 * 8]);
    async16(Bth + gb0 + k, &sBh[q0 * 8]);
    async16(Bth + gb1 + k, &sBh[q1 * 8]);
    async16(Btl + gb0 + k, &sBl[q0 * 8]);
    async16(Btl + gb1 + k, &sBl[q1 * 8]);
    asm volatile("s_waitcnt vmcnt(0)" ::: "memory");
    __syncthreads();

    short8 a_h[4], a_l[4], b_h[4], b_l[4];
#pragma unroll
    for (int mi = 0; mi < 4; ++mi) {
      int off = (wr * 64 + mi * 16 + lrow) * BK + quad * 8;
      a_h[mi] = *(const short8*)&sAh[off];
      a_l[mi] = *(const short8*)&sAl[off];
    }
#pragma unroll
    for (int ni = 0; ni < 4; ++ni) {
      int off = (wc * 64 + ni * 16 + lrow) * BK + quad * 8;
      b_h[ni] = *(const short8*)&sBh[off];
      b_l[ni] = *(const short8*)&sBl[off];
    }
#pragma unroll
    for (int mi = 0; mi < 4; ++mi)
#pragma unroll
      for (int ni = 0; ni < 4; ++ni) {
        acc[mi][ni] = __builtin_amdgcn_mfma_f32_16x16x32_bf16(a_h[mi], b_h[ni], acc[mi][ni], 0, 0, 0);
        acc[mi][ni] = __builtin_amdgcn_mfma_f32_16x16x32_bf16(a_h[mi], b_l[ni], acc[mi][ni], 0, 0, 0);
        acc[mi][ni] = __builtin_amdgcn_mfma_f32_16x16x32_bf16(a_l[mi], b_h[ni], acc[mi][ni], 0, 0, 0);
      }
    __syncthreads();
  }

  const bool has_epi = (Xh != nullptr);
#pragma unroll
  for (int mi = 0; mi < 4; ++mi)
#pragma unroll
    for (int ni = 0; ni < 4; ++ni) {
      const int gm_b = m0 + wr * 64 + mi * 16 + quad * 4;
      const int gn = n0 + wc * 64 + ni * 16 + lrow;
#pragma unroll
      for (int r = 0; r < 4; ++r) {
        const int gm = gm_b + r;
        const size_t g = (size_t)gm * NN + gn;
        float v = acc[mi][ni][r];
        if (has_epi) {
          v += (gm == gn) ? e0 : 0.f;
          v += e1 * (bf2f(Xh[g]) + bf2f(Xl[g]));
          v += e2 * (bf2f(Yh[g]) + bf2f(Yl[g]));
        }
        u16 hh = f2bf(v);
        Ch[g] = hh;
        Cl[g] = f2bf(v - bf2f(hh));
      }
    }
}

// ---- per-row 16th-largest value (exact top-k via iterative argmax) -------
extern "C" __global__ void __launch_bounds__(256) k_topk(
    const u16* __restrict__ Hh, const u16* __restrict__ Hl,
    float* __restrict__ thr) {
  __shared__ float vals[NN];
  __shared__ float wv[4];
  __shared__ int wi[4];
  const int row = blockIdx.x;
  const int tid = threadIdx.x;
  for (int j = tid; j < NN; j += 256) {
    size_t g = (size_t)row * NN + j;
    vals[j] = bf2f(Hh[g]) + bf2f(Hl[g]);
  }
  __syncthreads();
  for (int it = 0; it < 16; ++it) {
    float best = -3.0e38f;
    int bidx = 1 << 30;
    for (int j = tid; j < NN; j += 256) {
      float v = vals[j];
      if (v > best) { best = v; bidx = j; }
    }
#pragma unroll
    for (int off = 32; off > 0; off >>= 1) {
      float ov = __shfl_down(best, off);
      int oi = __shfl_down(bidx, off);
      if (ov > best || (ov == best && oi < bidx)) { best = ov; bidx = oi; }
    }
    if ((tid & 63) == 0) { wv[tid >> 6] = best; wi[tid >> 6] = bidx; }
    __syncthreads();
    if (tid == 0) {
      for (int w = 1; w < 4; ++w)
        if (wv[w] > wv[0] || (wv[w] == wv[0] && wi[w] < wi[0])) {
          wv[0] = wv[w]; wi[0] = wi[w];
        }
      vals[wi[0]] = -3.0e38f;      // mark taken (handles duplicates exactly)
      if (it == 15) thr[row] = wv[0];
    }
    __syncthreads();
  }
}

// ---- mask + symmetrize + add I + row-normalize ---------------------------
extern "C" __global__ void __launch_bounds__(256) k_final(
    const u16* __restrict__ Hh, const u16* __restrict__ Hl,   // heat rows
    const u16* __restrict__ Th, const u16* __restrict__ Tl,   // heat^T rows
    const float* __restrict__ thr, float* __restrict__ out) {
  __shared__ float v[NN];
  __shared__ float wsum[4];
  const int row = blockIdx.x;
  const int tid = threadIdx.x;
  const float ti = thr[row];
  float s = 0.f;
  for (int j = tid; j < NN; j += 256) {
    size_t g = (size_t)row * NN + j;
    float hij = bf2f(Hh[g]) + bf2f(Hl[g]);
    float hji = bf2f(Th[g]) + bf2f(Tl[g]);
    float val = (hij >= ti || hji >= thr[j]) ? 0.5f * (hij + hji) : 0.f;
    if (j == row) val += 1.f;
    v[j] = val;
    s += val;
  }
#pragma unroll
  for (int off = 32; off > 0; off >>= 1) s += __shfl_down(s, off);
  if ((tid & 63) == 0) wsum[tid >> 6] = s;
  __syncthreads();
  const float inv = 1.f / (wsum[0] + wsum[1] + wsum[2] + wsum[3]);
  for (int j = tid; j < NN; j += 256)
    out[(size_t)row * NN + j] = v[j] * inv;
}

extern "C" void kernel_launch(void* const* d_in, const int* in_sizes, int n_in,
                              void* d_out, int out_size, void* d_ws, size_t ws_size,
                              hipStream_t stream) {
  const float* adj = (const float*)d_in[0];
  char* ws = (char*)d_ws;
  const size_t PLANE = (size_t)NN * NN * sizeof(u16);   // 32 MiB
  u16* A_h = (u16*)(ws);
  u16* A_l = (u16*)(ws + PLANE);
  u16* B_h = (u16*)(ws + 2 * PLANE);
  u16* B_l = (u16*)(ws + 3 * PLANE);
  float* thr = (float*)(ws + 4 * PLANE);
  u16* C_h = (u16*)d_out;                                // d_out as plane slot
  u16* C_l = (u16*)((char*)d_out + PLANE);
  float* out = (float*)d_out;

  const dim3 b(256);
  const dim3 gT(64, 64);     // transpose tiles
  const dim3 gG(32, 32);     // gemm tiles
  const u16* nul = nullptr;

  // 1) M = -5/16 * adj -> A
  k_split_scale<<<dim3(NN * NN / 4 / 256), b, 0, stream>>>(adj, A_h, A_l, -0.3125f);
  // 2) M^T -> B
  k_transpose_combine<<<gT, b, 0, stream>>>(A_h, A_l, nul, nul, B_h, B_l, 1.f, 0.f);
  // 3) M2 = M*M -> d_out
  k_gemm<<<gG, b, 0, stream>>>(A_h, A_l, B_h, B_l, C_h, C_l,
                               nul, nul, nul, nul, 0.f, 0.f, 0.f);
  // 4) E2t = (M/6 + M2/24)^T -> B
  k_transpose_combine<<<gT, b, 0, stream>>>(A_h, A_l, C_h, C_l, B_h, B_l,
                                            1.f / 6.f, 1.f / 24.f);
  // 5) P = M2*E2 + (I + M + M2/2) -> A   (epilogue reads M in-place: safe)
  k_gemm<<<gG, b, 0, stream>>>(C_h, C_l, B_h, B_l, A_h, A_l,
                               A_h, A_l, C_h, C_l, 1.f, 1.f, 0.5f);
  // 6) P^T -> B
  k_transpose_combine<<<gT, b, 0, stream>>>(A_h, A_l, nul, nul, B_h, B_l, 1.f, 0.f);
  // 7) S1 = P*P -> d_out
  k_gemm<<<gG, b, 0, stream>>>(A_h, A_l, B_h, B_l, C_h, C_l,
                               nul, nul, nul, nul, 0.f, 0.f, 0.f);
  // 8) S1^T -> A
  k_transpose_combine<<<gT, b, 0, stream>>>(C_h, C_l, nul, nul, A_h, A_l, 1.f, 0.f);
  // 9) S2 = S1*S1 -> B
  k_gemm<<<gG, b, 0, stream>>>(C_h, C_l, A_h, A_l, B_h, B_l,
                               nul, nul, nul, nul, 0.f, 0.f, 0.f);
  // 10) S2^T -> d_out
  k_transpose_combine<<<gT, b, 0, stream>>>(B_h, B_l, nul, nul, C_h, C_l, 1.f, 0.f);
  // 11) S3 = S2*S2 -> A
  k_gemm<<<gG, b, 0, stream>>>(B_h, B_l, C_h, C_l, A_h, A_l,
                               nul, nul, nul, nul, 0.f, 0.f, 0.f);
  // 12) S3^T -> B
  k_transpose_combine<<<gT, b, 0, stream>>>(A_h, A_l, nul, nul, B_h, B_l, 1.f, 0.f);
  // 13) H = S3*S3 -> d_out   (heat)
  k_gemm<<<gG, b, 0, stream>>>(A_h, A_l, B_h, B_l, C_h, C_l,
                               nul, nul, nul, nul, 0.f, 0.f, 0.f);
  // 14) H^T -> A
  k_transpose_combine<<<gT, b, 0, stream>>>(C_h, C_l, nul, nul, A_h, A_l, 1.f, 0.f);
  // 15) H back out of d_out: (H^T)^T -> B  (frees d_out for the fp32 output)
  k_transpose_combine<<<gT, b, 0, stream>>>(A_h, A_l, nul, nul, B_h, B_l, 1.f, 0.f);
  // 16) per-row 16th-largest of H -> thr
  k_topk<<<dim3(NN), b, 0, stream>>>(B_h, B_l, thr);
  // 17) mask/sym/normalize -> out (overwrites d_out)
  k_final<<<dim3(NN), b, 0, stream>>>(B_h, B_l, A_h, A_l, thr, out);
}

// Round 2
// 1056.718 us; speedup vs baseline: 2.9181x; 2.9181x over previous
//
#include <hip/hip_runtime.h>
#include <stdint.h>

// HeatDiffusion: out = rownorm( mask_topk16_sym(expm(-5*adj)) symmetrized + I )
// N=4096. expm via scaling-and-squaring, s=2, deg-4 Taylor, IDENTITY-OFFSET:
//   Ms = -5*adj/4, M2 = Ms^2, G = Ms/6 + M2/24
//   Y0 = Ms + M2/2 + M2*G          (P = I + Y0)
//   Y1 = 2*Y0 + Y0^2               (P^2 = I + Y1)
//   Y2 = 2*Y1 + Y1^2               (heat = I + Y2)
// All GEMM operands have small entries (~1e-4) -> SINGLE bf16 MFMA pass per
// GEMM (no hi/lo 3-pass needed); linear terms added in fp32 epilogue from
// hi/lo planes. 4 GEMMs total (was 6 x 3 passes).
// Workspace: slotA (2 planes) | slotB (2 planes) | thr. d_out = 2 plane slots
// (C1) until k_final overwrites it with fp32 output.

#define NN 4096
#define BM 128
#define BN 128
#define BK 32

typedef unsigned short u16;
typedef __attribute__((ext_vector_type(8))) short short8;   // 8 bf16 = 4 VGPR
typedef __attribute__((ext_vector_type(4))) float f32x4;

__device__ __forceinline__ float bf2f(u16 u) {
  return __uint_as_float(((unsigned int)u) << 16);
}
__device__ __forceinline__ u16 f2bf(float f) {  // round-to-nearest-even
  unsigned int u = __float_as_uint(f);
  return (u16)((u + 0x7fffu + ((u >> 16) & 1u)) >> 16);
}

// async global->LDS, 16B per lane (global_load_lds_dwordx4). LDS dest must be
// wave-uniform base + lane*16 — chunk mapping guarantees that.
__device__ __forceinline__ void async16(const void* g, void* l) {
  auto gp = reinterpret_cast<const __attribute__((address_space(1))) unsigned int*>(
      reinterpret_cast<uintptr_t>(g));
  auto lp = reinterpret_cast<__attribute__((address_space(3))) unsigned int*>(
      reinterpret_cast<uintptr_t>(l));
  __builtin_amdgcn_global_load_lds(gp, lp, 16, 0, 0);
}

// ---- split fp32 -> bf16 hi/lo planes, with scale -------------------------
extern "C" __global__ void __launch_bounds__(256) k_split_scale(
    const float* __restrict__ src, u16* __restrict__ h, u16* __restrict__ l,
    float s) {
  int i = blockIdx.x * 256 + threadIdx.x;           // over N*N/4
  float4 v = ((const float4*)src)[i];
  v.x *= s; v.y *= s; v.z *= s; v.w *= s;
  ushort4 hv, lv;
  u16 t;
  t = f2bf(v.x); hv.x = t; lv.x = f2bf(v.x - bf2f(t));
  t = f2bf(v.y); hv.y = t; lv.y = f2bf(v.y - bf2f(t));
  t = f2bf(v.z); hv.z = t; lv.z = f2bf(v.z - bf2f(t));
  t = f2bf(v.w); hv.w = t; lv.w = f2bf(v.w - bf2f(t));
  ((ushort4*)h)[i] = hv;
  ((ushort4*)l)[i] = lv;
}

// ---- Z = transpose(sx*X + sy*Y), planes in/out ---------------------------
extern "C" __global__ void __launch_bounds__(256) k_transpose_combine(
    const u16* __restrict__ Xh, const u16* __restrict__ Xl,
    const u16* __restrict__ Yh, const u16* __restrict__ Yl,
    u16* __restrict__ Zh, u16* __restrict__ Zl, float sx, float sy) {
  __shared__ float tile[64][65];
  const int tx = threadIdx.x & 63;
  const int ty = threadIdx.x >> 6;
  const int r0 = blockIdx.y * 64, c0 = blockIdx.x * 64;
  for (int r = ty; r < 64; r += 4) {
    size_t g = (size_t)(r0 + r) * NN + (c0 + tx);
    float v = sx * (bf2f(Xh[g]) + bf2f(Xl[g]));
    if (Yh) v += sy * (bf2f(Yh[g]) + bf2f(Yl[g]));
    tile[r][tx] = v;
  }
  __syncthreads();
  for (int r = ty; r < 64; r += 4) {
    size_t g = (size_t)(c0 + r) * NN + (r0 + tx);
    float v = tile[tx][r];
    u16 hh = f2bf(v);
    Zh[g] = hh;
    Zl[g] = f2bf(v - bf2f(hh));
  }
}

// ---- C = A*B (+ epi: e0*I + e1*X + e2*Y), single bf16 pass ---------------
// A row-major hi plane; B passed TRANSPOSED (Bt row-major hi plane).
// 128x128 tile, BK=32, 4 waves, 4x4 mfma_f32_16x16x32_bf16 (m97 structure).
// Epilogue reads X,Y as hi+lo (fp32 precision) and writes C as hi/lo planes.
extern "C" __global__ void __launch_bounds__(256, 4) k_gemm(
    const u16* __restrict__ Ah, const u16* __restrict__ Bth,
    u16* __restrict__ Ch, u16* __restrict__ Cl,
    const u16* __restrict__ Xh, const u16* __restrict__ Xl,
    const u16* __restrict__ Yh, const u16* __restrict__ Yl,
    float e0, float e1, float e2) {
  __shared__ alignas(16) u16 sAh[BM * BK];
  __shared__ alignas(16) u16 sBh[BN * BK];

  const int tid  = threadIdx.x;
  const int lane = tid & 63;
  const int wave = tid >> 6;
  const int wr = wave >> 1, wc = wave & 1;   // wave's 64x64 quadrant
  const int quad = lane >> 4;
  const int lrow = lane & 15;
  const int m0 = blockIdx.x * BM;
  const int n0 = blockIdx.y * BN;

  f32x4 acc[4][4];
#pragma unroll
  for (int i = 0; i < 4; ++i)
#pragma unroll
    for (int j = 0; j < 4; ++j) acc[i][j] = (f32x4){0.f, 0.f, 0.f, 0.f};

  // staging: plane tile = 128x32 u16 = 8KB = 512 chunks of 16B; thread does
  // chunks tid and tid+256. chunk q -> row q>>2, cols (q&3)*8.., LDS elem q*8.
  const int q0 = tid, q1 = tid + 256;
  const int row0 = q0 >> 2, co0 = (q0 & 3) * 8;
  const int row1 = q1 >> 2, co1 = (q1 & 3) * 8;
  const size_t ga0 = (size_t)(m0 + row0) * NN + co0;
  const size_t ga1 = (size_t)(m0 + row1) * NN + co1;
  const size_t gb0 = (size_t)(n0 + row0) * NN + co0;
  const size_t gb1 = (size_t)(n0 + row1) * NN + co1;

  for (int k = 0; k < NN; k += BK) {
    async16(Ah + ga0 + k, &sAh[q0 * 8]);
    async16(Ah + ga1 + k, &sAh[q1 * 8]);
    async16(Bth + gb0 + k, &sBh[q0 * 8]);
    async16(Bth + gb1 + k, &sBh[q1 * 8]);
    asm volatile("s_waitcnt vmcnt(0)" ::: "memory");
    __syncthreads();

    short8 a_h[4], b_h[4];
#pragma unroll
    for (int mi = 0; mi < 4; ++mi) {
      int off = (wr * 64 + mi * 16 + lrow) * BK + quad * 8;
      a_h[mi] = *(const short8*)&sAh[off];
    }
#pragma unroll
    for (int ni = 0; ni < 4; ++ni) {
      int off = (wc * 64 + ni * 16 + lrow) * BK + quad * 8;
      b_h[ni] = *(const short8*)&sBh[off];
    }
#pragma unroll
    for (int mi = 0; mi < 4; ++mi)
#pragma unroll
      for (int ni = 0; ni < 4; ++ni)
        acc[mi][ni] = __builtin_amdgcn_mfma_f32_16x16x32_bf16(a_h[mi], b_h[ni], acc[mi][ni], 0, 0, 0);
    __syncthreads();
  }

  const bool hasX = (Xh != nullptr);
  const bool hasY = (Yh != nullptr);
#pragma unroll
  for (int mi = 0; mi < 4; ++mi)
#pragma unroll
    for (int ni = 0; ni < 4; ++ni) {
      const int gm_b = m0 + wr * 64 + mi * 16 + quad * 4;
      const int gn = n0 + wc * 64 + ni * 16 + lrow;
#pragma unroll
      for (int r = 0; r < 4; ++r) {
        const int gm = gm_b + r;
        const size_t g = (size_t)gm * NN + gn;
        float v = acc[mi][ni][r];
        if (gm == gn) v += e0;
        if (hasX) v += e1 * (bf2f(Xh[g]) + bf2f(Xl[g]));
        if (hasY) v += e2 * (bf2f(Yh[g]) + bf2f(Yl[g]));
        u16 hh = f2bf(v);
        Ch[g] = hh;
        Cl[g] = f2bf(v - bf2f(hh));
      }
    }
}

// ---- per-row 16th-largest of heat = (Y + I) (exact top-k via argmax) -----
extern "C" __global__ void __launch_bounds__(256) k_topk(
    const u16* __restrict__ Hh, const u16* __restrict__ Hl,
    float* __restrict__ thr) {
  __shared__ float vals[NN];
  __shared__ float wv[4];
  __shared__ int wi[4];
  const int row = blockIdx.x;
  const int tid = threadIdx.x;
  for (int j = tid; j < NN; j += 256) {
    size_t g = (size_t)row * NN + j;
    vals[j] = bf2f(Hh[g]) + bf2f(Hl[g]) + ((j == row) ? 1.f : 0.f);
  }
  __syncthreads();
  for (int it = 0; it < 16; ++it) {
    float best = -3.0e38f;
    int bidx = 1 << 30;
    for (int j = tid; j < NN; j += 256) {
      float v = vals[j];
      if (v > best) { best = v; bidx = j; }
    }
#pragma unroll
    for (int off = 32; off > 0; off >>= 1) {
      float ov = __shfl_down(best, off);
      int oi = __shfl_down(bidx, off);
      if (ov > best || (ov == best && oi < bidx)) { best = ov; bidx = oi; }
    }
    if ((tid & 63) == 0) { wv[tid >> 6] = best; wi[tid >> 6] = bidx; }
    __syncthreads();
    if (tid == 0) {
      for (int w = 1; w < 4; ++w)
        if (wv[w] > wv[0] || (wv[w] == wv[0] && wi[w] < wi[0])) {
          wv[0] = wv[w]; wi[0] = wi[w];
        }
      vals[wi[0]] = -3.0e38f;      // mark taken (handles duplicates exactly)
      if (it == 15) thr[row] = wv[0];
    }
    __syncthreads();
  }
}

// ---- mask + symmetrize + add I + row-normalize (heat = Y + I) ------------
extern "C" __global__ void __launch_bounds__(256) k_final(
    const u16* __restrict__ Hh, const u16* __restrict__ Hl,   // Y rows
    const u16* __restrict__ Th, const u16* __restrict__ Tl,   // Y^T rows
    const float* __restrict__ thr, float* __restrict__ out) {
  __shared__ float v[NN];
  __shared__ float wsum[4];
  const int row = blockIdx.x;
  const int tid = threadIdx.x;
  const float ti = thr[row];
  float s = 0.f;
  for (int j = tid; j < NN; j += 256) {
    size_t g = (size_t)row * NN + j;
    const float ind = (j == row) ? 1.f : 0.f;
    float hij = bf2f(Hh[g]) + bf2f(Hl[g]) + ind;
    float hji = bf2f(Th[g]) + bf2f(Tl[g]) + ind;
    float val = (hij >= ti || hji >= thr[j]) ? 0.5f * (hij + hji) : 0.f;
    val += ind;                                   // + eye after masking
    v[j] = val;
    s += val;
  }
#pragma unroll
  for (int off = 32; off > 0; off >>= 1) s += __shfl_down(s, off);
  if ((tid & 63) == 0) wsum[tid >> 6] = s;
  __syncthreads();
  const float inv = 1.f / (wsum[0] + wsum[1] + wsum[2] + wsum[3]);
  for (int j = tid; j < NN; j += 256)
    out[(size_t)row * NN + j] = v[j] * inv;
}

extern "C" void kernel_launch(void* const* d_in, const int* in_sizes, int n_in,
                              void* d_out, int out_size, void* d_ws, size_t ws_size,
                              hipStream_t stream) {
  const float* adj = (const float*)d_in[0];
  char* ws = (char*)d_ws;
  const size_t PLANE = (size_t)NN * NN * sizeof(u16);   // 32 MiB
  u16* A_h = (u16*)(ws);
  u16* A_l = (u16*)(ws + PLANE);
  u16* B_h = (u16*)(ws + 2 * PLANE);
  u16* B_l = (u16*)(ws + 3 * PLANE);
  float* thr = (float*)(ws + 4 * PLANE);
  u16* C_h = (u16*)d_out;                                // d_out as plane pair
  u16* C_l = (u16*)((char*)d_out + PLANE);
  float* out = (float*)d_out;

  const dim3 b(256);
  const dim3 gT(64, 64);     // transpose tiles
  const dim3 gG(32, 32);     // gemm tiles
  const u16* nul = nullptr;

  // 1) Ms = -5/4 * adj -> A (hi/lo)
  k_split_scale<<<dim3(NN * NN / 4 / 256), b, 0, stream>>>(adj, A_h, A_l, -1.25f);
  // 2) Ms^T -> B
  k_transpose_combine<<<gT, b, 0, stream>>>(A_h, A_l, nul, nul, B_h, B_l, 1.f, 0.f);
  // 3) M2 = Ms*Ms -> C1
  k_gemm<<<gG, b, 0, stream>>>(A_h, B_h, C_h, C_l,
                               nul, nul, nul, nul, 0.f, 0.f, 0.f);
  // 4) G^T = (Ms/6 + M2/24)^T -> B
  k_transpose_combine<<<gT, b, 0, stream>>>(A_h, A_l, C_h, C_l, B_h, B_l,
                                            1.f / 6.f, 1.f / 24.f);
  // 5) Y0 = M2*G + Ms + M2/2 -> A   (epilogue reads Ms in-place: same-elem, safe)
  k_gemm<<<gG, b, 0, stream>>>(C_h, B_h, A_h, A_l,
                               A_h, A_l, C_h, C_l, 0.f, 1.f, 0.5f);
  // 6) Y0^T -> B
  k_transpose_combine<<<gT, b, 0, stream>>>(A_h, A_l, nul, nul, B_h, B_l, 1.f, 0.f);
  // 7) Y1 = Y0*Y0 + 2*Y0 -> C1
  k_gemm<<<gG, b, 0, stream>>>(A_h, B_h, C_h, C_l,
                               A_h, A_l, nul, nul, 0.f, 2.f, 0.f);
  // 8) Y1^T -> B
  k_transpose_combine<<<gT, b, 0, stream>>>(C_h, C_l, nul, nul, B_h, B_l, 1.f, 0.f);
  // 9) Y2 = Y1*Y1 + 2*Y1 -> A   (heat = I + Y2)
  k_gemm<<<gG, b, 0, stream>>>(C_h, B_h, A_h, A_l,
                               C_h, C_l, nul, nul, 0.f, 2.f, 0.f);
  // 10) Y2^T -> B
  k_transpose_combine<<<gT, b, 0, stream>>>(A_h, A_l, nul, nul, B_h, B_l, 1.f, 0.f);
  // 11) per-row 16th-largest of heat -> thr
  k_topk<<<dim3(NN), b, 0, stream>>>(A_h, A_l, thr);
  // 12) mask/sym/normalize -> out (overwrites d_out; C1 dead)
  k_final<<<dim3(NN), b, 0, stream>>>(A_h, A_l, B_h, B_l, thr, out);
}

// Round 3
// 861.211 us; speedup vs baseline: 3.5806x; 1.2270x over previous
//
#include <hip/hip_runtime.h>
#include <stdint.h>

// HeatDiffusion: out = rownorm( mask_topk16_sym(expm(-5*adj)) symmetrized + I )
// N=4096. expm via scaling-and-squaring, s=2, deg-4 Taylor, identity-offset:
//   Ms = -5*adj/4, M2 = Ms^2, G = Ms/6 + M2/24
//   Y0 = Ms + M2/2 + M2*G    (P = I + Y0)
//   Y1 = 2*Y0 + Y0^2         (P^2   = I + Y1)
//   Y2 = 2*Y1 + Y1^2         (heat  = I + Y2)
// R3: single bf16 plane per matrix (error is top-k-flip-pinned, lo planes
// unnecessary); BK=64 (2x MFMA per barrier); all transposes fused into the
// producing kernel's epilogue (LDS-transposed coalesced dual-write).
// 4 GEMM dispatches + split + topk + final. Workspace: 4 planes + thr;
// d_out doubles as 2 plane slots until k_final overwrites it.

#define NN 4096
#define BM 128
#define BN 128
#define BK 64
#define TP 140   // u16 pitch of epilogue transpose tile (8B-aligned rows, ~2-way banks)

typedef unsigned short u16;
typedef __attribute__((ext_vector_type(8))) short short8;   // 8 bf16 = 4 VGPR
typedef __attribute__((ext_vector_type(4))) float f32x4;

__device__ __forceinline__ float bf2f(u16 u) {
  return __uint_as_float(((unsigned int)u) << 16);
}
__device__ __forceinline__ u16 f2bf(float f) {  // round-to-nearest-even
  unsigned int u = __float_as_uint(f);
  return (u16)((u + 0x7fffu + ((u >> 16) & 1u)) >> 16);
}

// async global->LDS, 16B/lane (global_load_lds_dwordx4); LDS dest must be
// wave-uniform base + lane*16 — chunk mapping guarantees that.
__device__ __forceinline__ void async16(const void* g, void* l) {
  auto gp = reinterpret_cast<const __attribute__((address_space(1))) unsigned int*>(
      reinterpret_cast<uintptr_t>(g));
  auto lp = reinterpret_cast<__attribute__((address_space(3))) unsigned int*>(
      reinterpret_cast<uintptr_t>(l));
  __builtin_amdgcn_global_load_lds(gp, lp, 16, 0, 0);
}

// ---- adj -> Ms (bf16) and Ms^T (bf16), fused ----------------------------
extern "C" __global__ void __launch_bounds__(256) k_split_tr(
    const float* __restrict__ src, u16* __restrict__ Z, u16* __restrict__ Zt,
    float s) {
  __shared__ float tile[64][65];
  const int tx = threadIdx.x & 63;
  const int ty = threadIdx.x >> 6;
  const int r0 = blockIdx.y * 64, c0 = blockIdx.x * 64;
  for (int r = ty; r < 64; r += 4) {
    size_t g = (size_t)(r0 + r) * NN + (c0 + tx);
    float v = s * src[g];
    tile[r][tx] = v;
    Z[g] = f2bf(v);
  }
  __syncthreads();
  for (int r = ty; r < 64; r += 4)
    Zt[(size_t)(c0 + r) * NN + (r0 + tx)] = f2bf(tile[tx][r]);
}

// ---- C = A*Bt^T + e1*X + e2*Y ; Ct = (tv*A*Bt^T + tx*X + ty*Y)^T ---------
// A, Bt row-major bf16 planes (Bt is B pre-transposed). 128x128 tile, BK=64,
// 4 waves x 4x4 mfma_f32_16x16x32_bf16. Epilogue dual-writes C (direct) and
// the transposed combination via an LDS transpose tile (coalesced 16B stores).
extern "C" __global__ void __launch_bounds__(256, 4) k_gemm(
    const u16* __restrict__ Ah, const u16* __restrict__ Bth,
    u16* __restrict__ C, u16* __restrict__ Ct,
    const u16* __restrict__ Xh, const u16* __restrict__ Yh,
    float e1, float e2, float tv, float tx, float ty) {
  // union: staging sA|sB (32KB) reused as 128x140 transpose tile (35KB)
  __shared__ alignas(16) u16 smem[128 * TP];
  u16* sA = smem;
  u16* sB = smem + BM * BK;

  const int tid  = threadIdx.x;
  const int lane = tid & 63;
  const int wave = tid >> 6;
  const int wr = wave >> 1, wc = wave & 1;
  const int quad = lane >> 4;
  const int lrow = lane & 15;

  // grouped swizzle: 16 bands of 8x8 tiles for L2/L3 panel locality
  const int bid = blockIdx.x;
  const int group = bid >> 6, inb = bid & 63;
  const int m0 = ((group & 3) * 8 + (inb & 7)) * BM;
  const int n0 = ((group >> 2) * 8 + (inb >> 3)) * BN;

  f32x4 acc[4][4];
#pragma unroll
  for (int i = 0; i < 4; ++i)
#pragma unroll
    for (int j = 0; j < 4; ++j) acc[i][j] = (f32x4){0.f, 0.f, 0.f, 0.f};

  // staging: tile 128x64 u16 = 16KB = 1024 16B-chunks; 4 chunks/thread/plane.
  // chunk q -> row q>>3, col (q&7)*8, LDS elem q*8 (contiguous in lane order).
  unsigned int ga[4], gb[4];
  int lo[4];
#pragma unroll
  for (int c = 0; c < 4; ++c) {
    int q = tid + c * 256;
    int row = q >> 3, col = (q & 7) * 8;
    ga[c] = (unsigned int)(m0 + row) * NN + col;
    gb[c] = (unsigned int)(n0 + row) * NN + col;
    lo[c] = q * 8;
  }

  for (int k = 0; k < NN; k += BK) {
#pragma unroll
    for (int c = 0; c < 4; ++c) {
      async16(Ah + ga[c] + k, sA + lo[c]);
      async16(Bth + gb[c] + k, sB + lo[c]);
    }
    asm volatile("s_waitcnt vmcnt(0)" ::: "memory");
    __syncthreads();

#pragma unroll
    for (int kk = 0; kk < 2; ++kk) {
      short8 a_h[4], b_h[4];
#pragma unroll
      for (int mi = 0; mi < 4; ++mi)
        a_h[mi] = *(const short8*)&sA[(wr * 64 + mi * 16 + lrow) * BK + kk * 32 + quad * 8];
#pragma unroll
      for (int ni = 0; ni < 4; ++ni)
        b_h[ni] = *(const short8*)&sB[(wc * 64 + ni * 16 + lrow) * BK + kk * 32 + quad * 8];
#pragma unroll
      for (int mi = 0; mi < 4; ++mi)
#pragma unroll
        for (int ni = 0; ni < 4; ++ni)
          acc[mi][ni] = __builtin_amdgcn_mfma_f32_16x16x32_bf16(a_h[mi], b_h[ni], acc[mi][ni], 0, 0, 0);
    }
    __syncthreads();   // also guards smem reuse by the epilogue on last iter
  }

  const bool hasX = (Xh != nullptr);
  const bool hasY = (Yh != nullptr);
#pragma unroll
  for (int mi = 0; mi < 4; ++mi)
#pragma unroll
    for (int ni = 0; ni < 4; ++ni) {
      const int lm = wr * 64 + mi * 16 + quad * 4;
      const int ln = wc * 64 + ni * 16 + lrow;
      const int gn = n0 + ln;
#pragma unroll
      for (int r = 0; r < 4; ++r) {
        const int gm = m0 + lm + r;
        const size_t g = (size_t)gm * NN + gn;
        float v = acc[mi][ni][r];
        float xv = hasX ? bf2f(Xh[g]) : 0.f;
        float yv = hasY ? bf2f(Yh[g]) : 0.f;
        C[g] = f2bf(v + e1 * xv + e2 * yv);
        smem[ln * TP + lm + r] = f2bf(tv * v + tx * xv + ty * yv);  // transposed tile
      }
    }
  __syncthreads();
  // coalesced Ct writes: wave covers local-n rows [wave*32, wave*32+32);
  // 16 lanes x 16B span one row-quad (4 rows x 128 u16 per pass).
  {
    const int sr = lane >> 4;      // 0..3
    const int c16 = lane & 15;     // 0..15
#pragma unroll
    for (int it = 0; it < 8; ++it) {
      const int row = wave * 32 + it * 4 + sr;
      const u16* src = &smem[row * TP + c16 * 8];
      uint2 lo8 = *(const uint2*)(src);
      uint2 hi8 = *(const uint2*)(src + 4);
      uint4 q; q.x = lo8.x; q.y = lo8.y; q.z = hi8.x; q.w = hi8.y;
      *(uint4*)(Ct + (size_t)(n0 + row) * NN + m0 + c16 * 8) = q;
    }
  }
}

// ---- per-row 16th-largest of heat = (Y2 + I) (exact, iterative argmax) ---
extern "C" __global__ void __launch_bounds__(256) k_topk(
    const u16* __restrict__ Hh, float* __restrict__ thr) {
  __shared__ float vals[NN];
  __shared__ float wv[4];
  __shared__ int wi[4];
  const int row = blockIdx.x;
  const int tid = threadIdx.x;
  for (int j = tid; j < NN; j += 256) {
    size_t g = (size_t)row * NN + j;
    vals[j] = bf2f(Hh[g]) + ((j == row) ? 1.f : 0.f);
  }
  __syncthreads();
  for (int it = 0; it < 16; ++it) {
    float best = -3.0e38f;
    int bidx = 1 << 30;
    for (int j = tid; j < NN; j += 256) {
      float v = vals[j];
      if (v > best) { best = v; bidx = j; }
    }
#pragma unroll
    for (int off = 32; off > 0; off >>= 1) {
      float ov = __shfl_down(best, off);
      int oi = __shfl_down(bidx, off);
      if (ov > best || (ov == best && oi < bidx)) { best = ov; bidx = oi; }
    }
    if ((tid & 63) == 0) { wv[tid >> 6] = best; wi[tid >> 6] = bidx; }
    __syncthreads();
    if (tid == 0) {
      for (int w = 1; w < 4; ++w)
        if (wv[w] > wv[0] || (wv[w] == wv[0] && wi[w] < wi[0])) {
          wv[0] = wv[w]; wi[0] = wi[w];
        }
      vals[wi[0]] = -3.0e38f;      // mark taken (handles duplicates exactly)
      if (it == 15) thr[row] = wv[0];
    }
    __syncthreads();
  }
}

// ---- mask + symmetrize + add I + row-normalize (heat = Y2 + I) -----------
extern "C" __global__ void __launch_bounds__(256) k_final(
    const u16* __restrict__ Hh,    // Y2 rows
    const u16* __restrict__ Th,    // Y2^T rows
    const float* __restrict__ thr, float* __restrict__ out) {
  __shared__ float v[NN];
  __shared__ float wsum[4];
  const int row = blockIdx.x;
  const int tid = threadIdx.x;
  const float ti = thr[row];
  float s = 0.f;
  for (int j = tid; j < NN; j += 256) {
    size_t g = (size_t)row * NN + j;
    const float ind = (j == row) ? 1.f : 0.f;
    float hij = bf2f(Hh[g]) + ind;
    float hji = bf2f(Th[g]) + ind;
    float val = (hij >= ti || hji >= thr[j]) ? 0.5f * (hij + hji) : 0.f;
    val += ind;                                   // + eye after masking
    v[j] = val;
    s += val;
  }
#pragma unroll
  for (int off = 32; off > 0; off >>= 1) s += __shfl_down(s, off);
  if ((tid & 63) == 0) wsum[tid >> 6] = s;
  __syncthreads();
  const float inv = 1.f / (wsum[0] + wsum[1] + wsum[2] + wsum[3]);
  for (int j = tid; j < NN; j += 256)
    out[(size_t)row * NN + j] = v[j] * inv;
}

extern "C" void kernel_launch(void* const* d_in, const int* in_sizes, int n_in,
                              void* d_out, int out_size, void* d_ws, size_t ws_size,
                              hipStream_t stream) {
  const float* adj = (const float*)d_in[0];
  char* ws = (char*)d_ws;
  const size_t PLANE = (size_t)NN * NN * sizeof(u16);   // 32 MiB
  u16* P0 = (u16*)(ws);
  u16* P1 = (u16*)(ws + PLANE);
  u16* P2 = (u16*)(ws + 2 * PLANE);
  u16* P3 = (u16*)(ws + 3 * PLANE);
  float* thr = (float*)(ws + 4 * PLANE);
  u16* C0 = (u16*)d_out;                                // d_out as plane pair
  u16* C1 = (u16*)((char*)d_out + PLANE);
  float* out = (float*)d_out;

  const dim3 b(256);
  const u16* nul = nullptr;

  // 1) Ms = -5/4*adj -> P0 ; Ms^T -> P1
  k_split_tr<<<dim3(64, 64), b, 0, stream>>>(adj, P0, P1, -1.25f);
  // 2) M2 = Ms*Ms -> P2 ; G^T = (Ms/6 + M2/24)^T -> P3
  k_gemm<<<dim3(1024), b, 0, stream>>>(P0, P1, P2, P3, P0, nul,
                                       0.f, 0.f, 1.f / 24.f, 1.f / 6.f, 0.f);
  // 3) Y0 = M2*G + Ms + M2/2 -> C0 ; Y0^T -> C1
  k_gemm<<<dim3(1024), b, 0, stream>>>(P2, P3, C0, C1, P0, P2,
                                       1.f, 0.5f, 1.f, 1.f, 0.5f);
  // 4) Y1 = Y0*Y0 + 2*Y0 -> P0 ; Y1^T -> P1
  k_gemm<<<dim3(1024), b, 0, stream>>>(C0, C1, P0, P1, C0, nul,
                                       2.f, 0.f, 1.f, 2.f, 0.f);
  // 5) Y2 = Y1*Y1 + 2*Y1 -> P2 ; Y2^T -> P3   (heat = I + Y2)
  k_gemm<<<dim3(1024), b, 0, stream>>>(P0, P1, P2, P3, P0, nul,
                                       2.f, 0.f, 1.f, 2.f, 0.f);
  // 6) per-row 16th-largest of heat -> thr
  k_topk<<<dim3(NN), b, 0, stream>>>(P2, thr);
  // 7) mask/sym/normalize -> out (overwrites d_out; C0/C1 dead)
  k_final<<<dim3(NN), b, 0, stream>>>(P2, P3, thr, out);
}

// Round 4
// 783.229 us; speedup vs baseline: 3.9371x; 1.0996x over previous
//
#include <hip/hip_runtime.h>
#include <stdint.h>

// HeatDiffusion: out = rownorm( mask_topk16_sym(expm(-5*adj)) symmetrized + I )
// N=4096. expm via scaling-and-squaring, s=2, deg-4 Taylor, identity-offset:
//   Ms = -5*adj/4, M2 = Ms^2, G = Ms/6 + M2/24
//   Y0 = Ms + M2/2 + M2*G    (P = I + Y0)
//   Y1 = 2*Y0 + Y0^2         (P^2   = I + Y1)
//   Y2 = 2*Y1 + Y1^2         (heat  = I + Y2)
// R4: XOR-swizzled LDS staging layout. global_load_lds pins LDS dest to
// chunk*16B, so we permute the global->chunk map: chunk q holds (row=q>>3,
// kgroup=(q&7)^(row&7)). Fragment reads XOR back; bank spread becomes 2-way
// (free) instead of 16-way. Everything else as R3.

#define NN 4096
#define BM 128
#define BN 128
#define BK 64
#define TP 140   // u16 pitch of epilogue transpose tile (8B-aligned rows)

typedef unsigned short u16;
typedef __attribute__((ext_vector_type(8))) short short8;   // 8 bf16 = 4 VGPR
typedef __attribute__((ext_vector_type(4))) float f32x4;

__device__ __forceinline__ float bf2f(u16 u) {
  return __uint_as_float(((unsigned int)u) << 16);
}
__device__ __forceinline__ u16 f2bf(float f) {  // round-to-nearest-even
  unsigned int u = __float_as_uint(f);
  return (u16)((u + 0x7fffu + ((u >> 16) & 1u)) >> 16);
}

// async global->LDS, 16B/lane (global_load_lds_dwordx4); LDS dest must be
// wave-uniform base + lane*16 — chunk mapping guarantees that.
__device__ __forceinline__ void async16(const void* g, void* l) {
  auto gp = reinterpret_cast<const __attribute__((address_space(1))) unsigned int*>(
      reinterpret_cast<uintptr_t>(g));
  auto lp = reinterpret_cast<__attribute__((address_space(3))) unsigned int*>(
      reinterpret_cast<uintptr_t>(l));
  __builtin_amdgcn_global_load_lds(gp, lp, 16, 0, 0);
}

// ---- adj -> Ms (bf16) and Ms^T (bf16), fused ----------------------------
extern "C" __global__ void __launch_bounds__(256) k_split_tr(
    const float* __restrict__ src, u16* __restrict__ Z, u16* __restrict__ Zt,
    float s) {
  __shared__ float tile[64][65];
  const int tx = threadIdx.x & 63;
  const int ty = threadIdx.x >> 6;
  const int r0 = blockIdx.y * 64, c0 = blockIdx.x * 64;
  for (int r = ty; r < 64; r += 4) {
    size_t g = (size_t)(r0 + r) * NN + (c0 + tx);
    float v = s * src[g];
    tile[r][tx] = v;
    Z[g] = f2bf(v);
  }
  __syncthreads();
  for (int r = ty; r < 64; r += 4)
    Zt[(size_t)(c0 + r) * NN + (r0 + tx)] = f2bf(tile[tx][r]);
}

// ---- C = A*Bt^T + e1*X + e2*Y ; Ct = (tv*A*Bt^T + tx*X + ty*Y)^T ---------
// A, Bt row-major bf16 planes (Bt is B pre-transposed). 128x128 tile, BK=64,
// 4 waves x 4x4 mfma_f32_16x16x32_bf16, XOR-swizzled LDS staging.
extern "C" __global__ void __launch_bounds__(256, 4) k_gemm(
    const u16* __restrict__ Ah, const u16* __restrict__ Bth,
    u16* __restrict__ C, u16* __restrict__ Ct,
    const u16* __restrict__ Xh, const u16* __restrict__ Yh,
    float e1, float e2, float tv, float tx, float ty) {
  // union: staging sA|sB (32KB) reused as 128x140 transpose tile (35KB)
  __shared__ alignas(16) u16 smem[128 * TP];
  u16* sA = smem;
  u16* sB = smem + BM * BK;

  const int tid  = threadIdx.x;
  const int lane = tid & 63;
  const int wave = tid >> 6;
  const int wr = wave >> 1, wc = wave & 1;
  const int quad = lane >> 4;
  const int lrow = lane & 15;

  // grouped swizzle: bands of 8x8 tiles for L2/L3 panel locality
  const int bid = blockIdx.x;
  const int group = bid >> 6, inb = bid & 63;
  const int m0 = ((group & 3) * 8 + (inb & 7)) * BM;
  const int n0 = ((group >> 2) * 8 + (inb >> 3)) * BN;

  f32x4 acc[4][4];
#pragma unroll
  for (int i = 0; i < 4; ++i)
#pragma unroll
    for (int j = 0; j < 4; ++j) acc[i][j] = (f32x4){0.f, 0.f, 0.f, 0.f};

  // staging: tile 128x64 u16 = 16KB = 1024 16B-chunks; 4 chunks/thread/plane.
  // XOR swizzle: chunk q holds global (row=q>>3, kgroup=(q&7)^(row&7)),
  // LDS dest = q*16B (contiguous in lane order, as global_load_lds needs).
  unsigned int ga[4], gb[4];
  int lo[4];
#pragma unroll
  for (int c = 0; c < 4; ++c) {
    int q = tid + c * 256;
    int row = q >> 3;
    int col = ((q & 7) ^ (row & 7)) * 8;
    ga[c] = (unsigned int)(m0 + row) * NN + col;
    gb[c] = (unsigned int)(n0 + row) * NN + col;
    lo[c] = q * 8;
  }

  for (int k = 0; k < NN; k += BK) {
#pragma unroll
    for (int c = 0; c < 4; ++c) {
      async16(Ah + ga[c] + k, sA + lo[c]);
      async16(Bth + gb[c] + k, sB + lo[c]);
    }
    asm volatile("s_waitcnt vmcnt(0)" ::: "memory");
    __syncthreads();

#pragma unroll
    for (int kk = 0; kk < 2; ++kk) {
      // swizzled column offset for this (kk, quad) at row parity lrow&7
      const int jsw = (((kk * 4 + quad) ^ (lrow & 7)) * 8);
      short8 a_h[4], b_h[4];
#pragma unroll
      for (int mi = 0; mi < 4; ++mi)
        a_h[mi] = *(const short8*)&sA[(wr * 64 + mi * 16 + lrow) * BK + jsw];
#pragma unroll
      for (int ni = 0; ni < 4; ++ni)
        b_h[ni] = *(const short8*)&sB[(wc * 64 + ni * 16 + lrow) * BK + jsw];
#pragma unroll
      for (int mi = 0; mi < 4; ++mi)
#pragma unroll
        for (int ni = 0; ni < 4; ++ni)
          acc[mi][ni] = __builtin_amdgcn_mfma_f32_16x16x32_bf16(a_h[mi], b_h[ni], acc[mi][ni], 0, 0, 0);
    }
    __syncthreads();   // also guards smem reuse by the epilogue on last iter
  }

  const bool hasX = (Xh != nullptr);
  const bool hasY = (Yh != nullptr);
#pragma unroll
  for (int mi = 0; mi < 4; ++mi)
#pragma unroll
    for (int ni = 0; ni < 4; ++ni) {
      const int lm = wr * 64 + mi * 16 + quad * 4;
      const int ln = wc * 64 + ni * 16 + lrow;
      const int gn = n0 + ln;
#pragma unroll
      for (int r = 0; r < 4; ++r) {
        const int gm = m0 + lm + r;
        const size_t g = (size_t)gm * NN + gn;
        float v = acc[mi][ni][r];
        float xv = hasX ? bf2f(Xh[g]) : 0.f;
        float yv = hasY ? bf2f(Yh[g]) : 0.f;
        C[g] = f2bf(v + e1 * xv + e2 * yv);
        smem[ln * TP + lm + r] = f2bf(tv * v + tx * xv + ty * yv);  // transposed tile
      }
    }
  __syncthreads();
  // coalesced Ct writes: wave covers local-n rows [wave*32, wave*32+32);
  // 16 lanes x 16B span one row-quad (4 rows x 128 u16 per pass).
  {
    const int sr = lane >> 4;      // 0..3
    const int c16 = lane & 15;     // 0..15
#pragma unroll
    for (int it = 0; it < 8; ++it) {
      const int row = wave * 32 + it * 4 + sr;
      const u16* src = &smem[row * TP + c16 * 8];
      uint2 lo8 = *(const uint2*)(src);
      uint2 hi8 = *(const uint2*)(src + 4);
      uint4 q; q.x = lo8.x; q.y = lo8.y; q.z = hi8.x; q.w = hi8.y;
      *(uint4*)(Ct + (size_t)(n0 + row) * NN + m0 + c16 * 8) = q;
    }
  }
}

// ---- per-row 16th-largest of heat = (Y2 + I) (exact, iterative argmax) ---
extern "C" __global__ void __launch_bounds__(256) k_topk(
    const u16* __restrict__ Hh, float* __restrict__ thr) {
  __shared__ float vals[NN];
  __shared__ float wv[4];
  __shared__ int wi[4];
  const int row = blockIdx.x;
  const int tid = threadIdx.x;
  for (int j = tid; j < NN; j += 256) {
    size_t g = (size_t)row * NN + j;
    vals[j] = bf2f(Hh[g]) + ((j == row) ? 1.f : 0.f);
  }
  __syncthreads();
  for (int it = 0; it < 16; ++it) {
    float best = -3.0e38f;
    int bidx = 1 << 30;
    for (int j = tid; j < NN; j += 256) {
      float v = vals[j];
      if (v > best) { best = v; bidx = j; }
    }
#pragma unroll
    for (int off = 32; off > 0; off >>= 1) {
      float ov = __shfl_down(best, off);
      int oi = __shfl_down(bidx, off);
      if (ov > best || (ov == best && oi < bidx)) { best = ov; bidx = oi; }
    }
    if ((tid & 63) == 0) { wv[tid >> 6] = best; wi[tid >> 6] = bidx; }
    __syncthreads();
    if (tid == 0) {
      for (int w = 1; w < 4; ++w)
        if (wv[w] > wv[0] || (wv[w] == wv[0] && wi[w] < wi[0])) {
          wv[0] = wv[w]; wi[0] = wi[w];
        }
      vals[wi[0]] = -3.0e38f;      // mark taken (handles duplicates exactly)
      if (it == 15) thr[row] = wv[0];
    }
    __syncthreads();
  }
}

// ---- mask + symmetrize + add I + row-normalize (heat = Y2 + I) -----------
extern "C" __global__ void __launch_bounds__(256) k_final(
    const u16* __restrict__ Hh,    // Y2 rows
    const u16* __restrict__ Th,    // Y2^T rows
    const float* __restrict__ thr, float* __restrict__ out) {
  __shared__ float v[NN];
  __shared__ float wsum[4];
  const int row = blockIdx.x;
  const int tid = threadIdx.x;
  const float ti = thr[row];
  float s = 0.f;
  for (int j = tid; j < NN; j += 256) {
    size_t g = (size_t)row * NN + j;
    const float ind = (j == row) ? 1.f : 0.f;
    float hij = bf2f(Hh[g]) + ind;
    float hji = bf2f(Th[g]) + ind;
    float val = (hij >= ti || hji >= thr[j]) ? 0.5f * (hij + hji) : 0.f;
    val += ind;                                   // + eye after masking
    v[j] = val;
    s += val;
  }
#pragma unroll
  for (int off = 32; off > 0; off >>= 1) s += __shfl_down(s, off);
  if ((tid & 63) == 0) wsum[tid >> 6] = s;
  __syncthreads();
  const float inv = 1.f / (wsum[0] + wsum[1] + wsum[2] + wsum[3]);
  for (int j = tid; j < NN; j += 256)
    out[(size_t)row * NN + j] = v[j] * inv;
}

extern "C" void kernel_launch(void* const* d_in, const int* in_sizes, int n_in,
                              void* d_out, int out_size, void* d_ws, size_t ws_size,
                              hipStream_t stream) {
  const float* adj = (const float*)d_in[0];
  char* ws = (char*)d_ws;
  const size_t PLANE = (size_t)NN * NN * sizeof(u16);   // 32 MiB
  u16* P0 = (u16*)(ws);
  u16* P1 = (u16*)(ws + PLANE);
  u16* P2 = (u16*)(ws + 2 * PLANE);
  u16* P3 = (u16*)(ws + 3 * PLANE);
  float* thr = (float*)(ws + 4 * PLANE);
  u16* C0 = (u16*)d_out;                                // d_out as plane pair
  u16* C1 = (u16*)((char*)d_out + PLANE);
  float* out = (float*)d_out;

  const dim3 b(256);
  const u16* nul = nullptr;

  // 1) Ms = -5/4*adj -> P0 ; Ms^T -> P1
  k_split_tr<<<dim3(64, 64), b, 0, stream>>>(adj, P0, P1, -1.25f);
  // 2) M2 = Ms*Ms -> P2 ; G^T = (Ms/6 + M2/24)^T -> P3
  k_gemm<<<dim3(1024), b, 0, stream>>>(P0, P1, P2, P3, P0, nul,
                                       0.f, 0.f, 1.f / 24.f, 1.f / 6.f, 0.f);
  // 3) Y0 = M2*G + Ms + M2/2 -> C0 ; Y0^T -> C1
  k_gemm<<<dim3(1024), b, 0, stream>>>(P2, P3, C0, C1, P0, P2,
                                       1.f, 0.5f, 1.f, 1.f, 0.5f);
  // 4) Y1 = Y0*Y0 + 2*Y0 -> P0 ; Y1^T -> P1
  k_gemm<<<dim3(1024), b, 0, stream>>>(C0, C1, P0, P1, C0, nul,
                                       2.f, 0.f, 1.f, 2.f, 0.f);
  // 5) Y2 = Y1*Y1 + 2*Y1 -> P2 ; Y2^T -> P3   (heat = I + Y2)
  k_gemm<<<dim3(1024), b, 0, stream>>>(P0, P1, P2, P3, P0, nul,
                                       2.f, 0.f, 1.f, 2.f, 0.f);
  // 6) per-row 16th-largest of heat -> thr
  k_topk<<<dim3(NN), b, 0, stream>>>(P2, thr);
  // 7) mask/sym/normalize -> out (overwrites d_out; C0/C1 dead)
  k_final<<<dim3(NN), b, 0, stream>>>(P2, P3, thr, out);
}

// Round 5
// 763.566 us; speedup vs baseline: 4.0384x; 1.0258x over previous
//
#include <hip/hip_runtime.h>
#include <stdint.h>

// HeatDiffusion: out = rownorm( mask_topk16_sym(expm(-5*adj)) symmetrized + I )
// N=4096. expm via scaling-and-squaring, s=2, deg-4 Taylor, identity-offset:
//   Ms = -5*adj/4, M2 = Ms^2, G = Ms/6 + M2/24
//   Y0 = Ms + M2/2 + M2*G    (P = I + Y0)
//   Y1 = 2*Y0 + Y0^2         (P^2   = I + Y1)
//   Y2 = 2*Y1 + Y1^2         (heat  = I + Y2)
// R5: GEMMs in MX-FP8 (mfma_scale_f32_32x32x64_f8f6f4, unit E8M0 scales) at
// ~2x bf16 rate. Precision carried by bf16 planes through fp32 epilogues;
// MFMA computes only small quadratic terms. Compile-time global power-of-2
// scales keep operands in e4m3 range (hard analytic bounds, no clamping
// needed). BK=128 keeps LDS rows at 128B -> R4 XOR swizzle stays ~2-way.

#define NN 4096
#define BM 128
#define BN 128
#define TP 140    // u16 pitch, bf16 epilogue-transpose tile (last GEMM)
#define TP8 144   // byte pitch, fp8 epilogue-transpose tile

typedef unsigned short u16;
typedef unsigned char u8;
typedef __attribute__((ext_vector_type(8))) int v8i;
typedef __attribute__((ext_vector_type(16))) float v16f;

__device__ __forceinline__ float bf2f(u16 u) {
  return __uint_as_float(((unsigned int)u) << 16);
}
__device__ __forceinline__ u16 f2bf(float f) {  // round-to-nearest-even
  unsigned int u = __float_as_uint(f);
  return (u16)((u + 0x7fffu + ((u >> 16) & 1u)) >> 16);
}
// float -> OCP e4m3fn, RNE. Caller guarantees |f| <= 440 and finite.
__device__ __forceinline__ u8 f2e4m3(float f) {
  unsigned int u = __float_as_uint(f);
  unsigned int sign = (u >> 24) & 0x80u;
  int e8 = (int)((u >> 23) & 0xFF) - 127 + 7;
  if (e8 >= 1) {
    unsigned int man = u & 0x7FFFFFu;
    unsigned int m = man >> 20;
    unsigned int rem = man & 0xFFFFFu;
    if (rem > 0x80000u || (rem == 0x80000u && (m & 1u))) ++m;
    if (m == 8u) { m = 0u; ++e8; }
    return (u8)(sign | ((unsigned)e8 << 3) | m);
  } else {
    float af = __uint_as_float(u & 0x7FFFFFFFu);
    int q = (int)rintf(af * 512.0f);          // subnormal quantum 2^-9
    if (q >= 8) return (u8)(sign | (1u << 3)); // rounds up to min normal
    return (u8)(sign | (unsigned)q);
  }
}

// async global->LDS, 16B/lane (global_load_lds_dwordx4); LDS dest must be
// wave-uniform base + lane*16 — chunk mapping guarantees that.
__device__ __forceinline__ void async16(const void* g, void* l) {
  auto gp = reinterpret_cast<const __attribute__((address_space(1))) unsigned int*>(
      reinterpret_cast<uintptr_t>(g));
  auto lp = reinterpret_cast<__attribute__((address_space(3))) unsigned int*>(
      reinterpret_cast<uintptr_t>(l));
  __builtin_amdgcn_global_load_lds(gp, lp, 16, 0, 0);
}

// ---- adj -> Ms bf16, Ms fp8 (x2^20), Ms^T fp8 (x2^20), fused -------------
extern "C" __global__ void __launch_bounds__(256) k_split_tr(
    const float* __restrict__ src, u16* __restrict__ Z16,
    u8* __restrict__ Z8, u8* __restrict__ Zt8, float s, float s8) {
  __shared__ float tile[64][65];
  const int tx = threadIdx.x & 63;
  const int ty = threadIdx.x >> 6;
  const int r0 = blockIdx.y * 64, c0 = blockIdx.x * 64;
  for (int r = ty; r < 64; r += 4) {
    size_t g = (size_t)(r0 + r) * NN + (c0 + tx);
    float v = s * src[g];
    tile[r][tx] = v;
    Z16[g] = f2bf(v);
    Z8[g] = f2e4m3(v * s8);
  }
  __syncthreads();
  for (int r = ty; r < 64; r += 4)
    Zt8[(size_t)(c0 + r) * NN + (r0 + tx)] = f2e4m3(tile[tx][r] * s8);
}

// ---- FP8 GEMM: vc = accScale*(A8*Bt8^T) + e1*X + e2*Y --------------------
// writes C16 = bf16(vc); if C8: C8 = fp8(vc*sC8), C8t = fp8(t*sT8)^T;
// if Ct16 (last): Ct16 = bf16(t)^T, where t = tv*acc*accScale + tx*X + ty*Y.
// 128x128 tile, BK=128, 4 waves x (2x2 of 32x32x64 f8f6f4, unit scales).
extern "C" __global__ void __launch_bounds__(256, 3) k_gemm8(
    const u8* __restrict__ A8, const u8* __restrict__ Bt8,
    u16* __restrict__ C16, u8* __restrict__ C8, u8* __restrict__ C8t,
    u16* __restrict__ Ct16,
    const u16* __restrict__ X16, const u16* __restrict__ Y16,
    float accScale, float e1, float e2,
    float tv, float tx, float ty, float sC8, float sT8) {
  // union: staging sA|sB (32KB) / fp8 transpose tile (18KB) / bf16 tile (35KB)
  __shared__ alignas(16) u16 smem16[128 * TP];
  u8* smem8 = (u8*)smem16;
  u8* sA = smem8;
  u8* sB = smem8 + 16384;

  const int tid  = threadIdx.x;
  const int lane = tid & 63;
  const int wave = tid >> 6;
  const int wr = wave >> 1, wc = wave & 1;
  const int half = lane >> 5;     // K-half of the MFMA fragment
  const int r31 = lane & 31;

  // grouped swizzle: bands of 8x8 tiles for L2/L3 panel locality
  const int bid = blockIdx.x;
  const int group = bid >> 6, inb = bid & 63;
  const int m0 = ((group & 3) * 8 + (inb & 7)) * BM;
  const int n0 = ((group >> 2) * 8 + (inb >> 3)) * BN;

  v16f acc[2][2];
#pragma unroll
  for (int i = 0; i < 2; ++i)
#pragma unroll
    for (int j = 0; j < 2; ++j)
#pragma unroll
      for (int r = 0; r < 16; ++r) acc[i][j][r] = 0.f;

  // staging: plane tile 128x128 fp8 = 16KB = 1024 chunks of 16B; 4/thread.
  // XOR swizzle: chunk q holds global (row=q>>3, col16=((q&7)^(row&7))*16).
  unsigned int ga[4], gb[4];
  int lo[4];
#pragma unroll
  for (int c = 0; c < 4; ++c) {
    int q = tid + c * 256;
    int row = q >> 3;
    int col = ((q & 7) ^ (row & 7)) * 16;
    ga[c] = (unsigned int)(m0 + row) * NN + col;
    gb[c] = (unsigned int)(n0 + row) * NN + col;
    lo[c] = q * 16;
  }

  for (int k = 0; k < NN; k += 128) {
#pragma unroll
    for (int c = 0; c < 4; ++c) {
      async16(A8 + ga[c] + k, sA + lo[c]);
      async16(Bt8 + gb[c] + k, sB + lo[c]);
    }
    asm volatile("s_waitcnt vmcnt(0)" ::: "memory");
    __syncthreads();

#pragma unroll
    for (int kb = 0; kb < 2; ++kb) {
      v8i af[2], bf_[2];
#pragma unroll
      for (int mi = 0; mi < 2; ++mi) {
        const int r = wr * 64 + mi * 32 + r31;
        const int c0 = (kb * 4 + half * 2) ^ (r & 7);   // even pre-XOR => c1=c0^1
        const uint4 q0 = *(const uint4*)&sA[r * 128 + c0 * 16];
        const uint4 q1 = *(const uint4*)&sA[r * 128 + (c0 ^ 1) * 16];
        af[mi] = (v8i){(int)q0.x, (int)q0.y, (int)q0.z, (int)q0.w,
                       (int)q1.x, (int)q1.y, (int)q1.z, (int)q1.w};
      }
#pragma unroll
      for (int ni = 0; ni < 2; ++ni) {
        const int r = wc * 64 + ni * 32 + r31;
        const int c0 = (kb * 4 + half * 2) ^ (r & 7);
        const uint4 q0 = *(const uint4*)&sB[r * 128 + c0 * 16];
        const uint4 q1 = *(const uint4*)&sB[r * 128 + (c0 ^ 1) * 16];
        bf_[ni] = (v8i){(int)q0.x, (int)q0.y, (int)q0.z, (int)q0.w,
                        (int)q1.x, (int)q1.y, (int)q1.z, (int)q1.w};
      }
#pragma unroll
      for (int mi = 0; mi < 2; ++mi)
#pragma unroll
        for (int ni = 0; ni < 2; ++ni)
          acc[mi][ni] = __builtin_amdgcn_mfma_scale_f32_32x32x64_f8f6f4(
              af[mi], bf_[ni], acc[mi][ni], 0, 0, 0, 0x7F, 0, 0x7F);
    }
    __syncthreads();   // also guards smem reuse by the epilogue on last iter
  }

  const bool hasX = (X16 != nullptr);
  const bool hasY = (Y16 != nullptr);
  const bool last = (Ct16 != nullptr);
#pragma unroll
  for (int mi = 0; mi < 2; ++mi)
#pragma unroll
    for (int ni = 0; ni < 2; ++ni) {
      const int gnl = wc * 64 + ni * 32 + r31;
      const int gn = n0 + gnl;
#pragma unroll
      for (int reg = 0; reg < 16; ++reg) {
        const int rowl = (reg & 3) + 8 * (reg >> 2) + 4 * half;
        const int gml = wr * 64 + mi * 32 + rowl;
        const size_t g = (size_t)(m0 + gml) * NN + gn;
        const float vraw = acc[mi][ni][reg] * accScale;
        const float xv = hasX ? bf2f(X16[g]) : 0.f;
        const float yv = hasY ? bf2f(Y16[g]) : 0.f;
        const float vc = vraw + e1 * xv + e2 * yv;
        const float t = tv * vraw + tx * xv + ty * yv;
        C16[g] = f2bf(vc);
        if (last) {
          smem16[gnl * TP + gml] = f2bf(t);
        } else {
          C8[g] = f2e4m3(vc * sC8);
          smem8[gnl * TP8 + gml] = f2e4m3(t * sT8);
        }
      }
    }
  __syncthreads();

  if (last) {
    // coalesced bf16 Ct: wave covers local-n rows [wave*32, wave*32+32)
    const int sr = lane >> 4;
    const int c16 = lane & 15;
#pragma unroll
    for (int it = 0; it < 8; ++it) {
      const int row = wave * 32 + it * 4 + sr;
      const u16* srcp = &smem16[row * TP + c16 * 8];
      uint2 lo8 = *(const uint2*)(srcp);
      uint2 hi8 = *(const uint2*)(srcp + 4);
      uint4 q; q.x = lo8.x; q.y = lo8.y; q.z = hi8.x; q.w = hi8.y;
      *(uint4*)(Ct16 + (size_t)(n0 + row) * NN + m0 + c16 * 8) = q;
    }
  } else {
    // coalesced fp8 C8t: 1024 chunks of 16B, 4/thread
#pragma unroll
    for (int cc = 0; cc < 4; ++cc) {
      const int qq = tid + cc * 256;
      const int row = qq >> 3, p = qq & 7;
      uint4 v = *(const uint4*)&smem8[row * TP8 + p * 16];
      *(uint4*)&C8t[(size_t)(n0 + row) * NN + m0 + p * 16] = v;
    }
  }
}

// ---- per-row 16th-largest of heat = (Y2 + I) (exact, iterative argmax) ---
extern "C" __global__ void __launch_bounds__(256) k_topk(
    const u16* __restrict__ Hh, float* __restrict__ thr) {
  __shared__ float vals[NN];
  __shared__ float wv[4];
  __shared__ int wi[4];
  const int row = blockIdx.x;
  const int tid = threadIdx.x;
  for (int j = tid; j < NN; j += 256) {
    size_t g = (size_t)row * NN + j;
    vals[j] = bf2f(Hh[g]) + ((j == row) ? 1.f : 0.f);
  }
  __syncthreads();
  for (int it = 0; it < 16; ++it) {
    float best = -3.0e38f;
    int bidx = 1 << 30;
    for (int j = tid; j < NN; j += 256) {
      float v = vals[j];
      if (v > best) { best = v; bidx = j; }
    }
#pragma unroll
    for (int off = 32; off > 0; off >>= 1) {
      float ov = __shfl_down(best, off);
      int oi = __shfl_down(bidx, off);
      if (ov > best || (ov == best && oi < bidx)) { best = ov; bidx = oi; }
    }
    if ((tid & 63) == 0) { wv[tid >> 6] = best; wi[tid >> 6] = bidx; }
    __syncthreads();
    if (tid == 0) {
      for (int w = 1; w < 4; ++w)
        if (wv[w] > wv[0] || (wv[w] == wv[0] && wi[w] < wi[0])) {
          wv[0] = wv[w]; wi[0] = wi[w];
        }
      vals[wi[0]] = -3.0e38f;      // mark taken (handles duplicates exactly)
      if (it == 15) thr[row] = wv[0];
    }
    __syncthreads();
  }
}

// ---- mask + symmetrize + add I + row-normalize (heat = Y2 + I) -----------
extern "C" __global__ void __launch_bounds__(256) k_final(
    const u16* __restrict__ Hh,    // Y2 rows
    const u16* __restrict__ Th,    // Y2^T rows
    const float* __restrict__ thr, float* __restrict__ out) {
  __shared__ float v[NN];
  __shared__ float wsum[4];
  const int row = blockIdx.x;
  const int tid = threadIdx.x;
  const float ti = thr[row];
  float s = 0.f;
  for (int j = tid; j < NN; j += 256) {
    size_t g = (size_t)row * NN + j;
    const float ind = (j == row) ? 1.f : 0.f;
    float hij = bf2f(Hh[g]) + ind;
    float hji = bf2f(Th[g]) + ind;
    float val = (hij >= ti || hji >= thr[j]) ? 0.5f * (hij + hji) : 0.f;
    val += ind;                                   // + eye after masking
    v[j] = val;
    s += val;
  }
#pragma unroll
  for (int off = 32; off > 0; off >>= 1) s += __shfl_down(s, off);
  if ((tid & 63) == 0) wsum[tid >> 6] = s;
  __syncthreads();
  const float inv = 1.f / (wsum[0] + wsum[1] + wsum[2] + wsum[3]);
  for (int j = tid; j < NN; j += 256)
    out[(size_t)row * NN + j] = v[j] * inv;
}

extern "C" void kernel_launch(void* const* d_in, const int* in_sizes, int n_in,
                              void* d_out, int out_size, void* d_ws, size_t ws_size,
                              hipStream_t stream) {
  const float* adj = (const float*)d_in[0];
  char* ws = (char*)d_ws;
  const size_t U = (size_t)NN * NN;             // 16 MiB unit (fp8 plane size)
  // bf16 plane = 2 units, fp8 plane = 1 unit. ws >= 8 units + 16 KB.
  u16* Ms16  = (u16*)(ws);                      // u0-1 (bf16)
  u8*  MsF   = (u8*)(ws + 2 * U);               // u2
  u8*  MstF  = (u8*)(ws + 3 * U);               // u3
  u8*  M2F   = (u8*)(ws + 4 * U);               // u4
  u8*  GtF   = (u8*)(ws + 5 * U);               // u5
  u8*  Y0F   = (u8*)(ws + 6 * U);               // u6
  u8*  Y0tF  = (u8*)(ws + 7 * U);               // u7
  u16* Y1_16 = (u16*)(ws);                      // u0-1 (Ms16 dead after G2)
  u8*  Y1F   = (u8*)(ws + 2 * U);               // u2 (MsF dead)
  u8*  Y1tF  = (u8*)(ws + 3 * U);               // u3 (MstF dead)
  u16* Y2_16 = (u16*)(ws + 4 * U);              // u4-5 (M2F/GtF dead)
  u16* Y2t16 = (u16*)(ws + 6 * U);              // u6-7 (Y0F/Y0tF dead)
  float* thr = (float*)(ws + 8 * U);
  u16* M2_16 = (u16*)d_out;                     // d_out lower 32MB, scratch
  u16* Y0_16 = (u16*)((char*)d_out + 2 * U);    // d_out upper 32MB, scratch
  float* out = (float*)d_out;

  const dim3 b(256);
  const u16* n16 = nullptr;
  u8* n8 = nullptr;

  // 1) Ms = -5/4*adj: bf16 -> Ms16, fp8*2^20 -> MsF, (Ms^T)*2^20 -> MstF
  k_split_tr<<<dim3(64, 64), b, 0, stream>>>(adj, Ms16, MsF, MstF,
                                             -1.25f, 0x1p20f);
  // 2) M2 = Ms*Ms; C=M2 (bf16 + fp8*2^20); Ct = G^T = (Ms/6 + M2/24)^T fp8*2^22
  k_gemm8<<<dim3(1024), b, 0, stream>>>(MsF, MstF, M2_16, M2F, GtF, (u16*)nullptr,
                                        Ms16, n16,
                                        0x1p-40f, 0.f, 0.f,
                                        1.f / 24.f, 1.f / 6.f, 0.f,
                                        0x1p20f, 0x1p22f);
  // 3) Y0 = M2*G + Ms + M2/2; C=Y0 (bf16 + fp8*2^19); Ct = Y0^T fp8*2^19
  k_gemm8<<<dim3(1024), b, 0, stream>>>(M2F, GtF, Y0_16, Y0F, Y0tF, (u16*)nullptr,
                                        Ms16, M2_16,
                                        0x1p-42f, 1.f, 0.5f,
                                        1.f, 1.f, 0.5f,
                                        0x1p19f, 0x1p19f);
  // 4) Y1 = Y0*Y0 + 2*Y0; C=Y1 (bf16 + fp8*2^17); Ct = Y1^T fp8*2^17
  k_gemm8<<<dim3(1024), b, 0, stream>>>(Y0F, Y0tF, Y1_16, Y1F, Y1tF, (u16*)nullptr,
                                        Y0_16, n16,
                                        0x1p-38f, 2.f, 0.f,
                                        1.f, 2.f, 0.f,
                                        0x1p17f, 0x1p17f);
  // 5) Y2 = Y1*Y1 + 2*Y1; C=Y2 bf16; Ct = Y2^T bf16 (terminal, no fp8)
  k_gemm8<<<dim3(1024), b, 0, stream>>>(Y1F, Y1tF, Y2_16, n8, n8, Y2t16,
                                        Y1_16, n16,
                                        0x1p-34f, 2.f, 0.f,
                                        1.f, 2.f, 0.f,
                                        1.f, 1.f);
  // 6) per-row 16th-largest of heat -> thr
  k_topk<<<dim3(NN), b, 0, stream>>>(Y2_16, thr);
  // 7) mask/sym/normalize -> out (overwrites d_out; M2_16/Y0_16 dead)
  k_final<<<dim3(NN), b, 0, stream>>>(Y2_16, Y2t16, thr, out);
}

// Round 6
// 729.396 us; speedup vs baseline: 4.2276x; 1.0468x over previous
//
#include <hip/hip_runtime.h>
#include <stdint.h>

// HeatDiffusion: out = rownorm( mask_topk16_sym(expm(-5*adj)) symmetrized + I )
// N=4096. expm via scaling-and-squaring, s=2, deg-4 Taylor, identity-offset:
//   Ms = -5*adj/4, M2 = Ms^2, G = Ms/6 + M2/24
//   Y0 = Ms + M2/2 + M2*G    (P = I + Y0)
//   Y1 = 2*Y0 + Y0^2         (P^2   = I + Y1)
//   Y2 = 2*Y1 + Y1^2         (heat  = I + Y2)
// R6: fp8 GEMM switched 32x32x64 -> 16x16x128 (m148/m97 structure): 4x4 acc
// tile per wave restores fragment-read:MFMA ratio 1:1 (R5's 2:1 starved the
// MFMA pipe). Same unit-scale MX path, same compile-time power-of-2 operand
// scales, same XOR-swizzled staging (conflict-free per 8-lane phase).

#define NN 4096
#define BM 128
#define BN 128
#define TP 140    // u16 pitch, bf16 epilogue-transpose tile (last GEMM)
#define TP8 144   // byte pitch, fp8 epilogue-transpose tile

typedef unsigned short u16;
typedef unsigned char u8;
typedef __attribute__((ext_vector_type(8))) int v8i;
typedef __attribute__((ext_vector_type(4))) float f32x4;

__device__ __forceinline__ float bf2f(u16 u) {
  return __uint_as_float(((unsigned int)u) << 16);
}
__device__ __forceinline__ u16 f2bf(float f) {  // round-to-nearest-even
  unsigned int u = __float_as_uint(f);
  return (u16)((u + 0x7fffu + ((u >> 16) & 1u)) >> 16);
}
// float -> OCP e4m3fn, RNE. Caller guarantees |f| <= 440 and finite.
__device__ __forceinline__ u8 f2e4m3(float f) {
  unsigned int u = __float_as_uint(f);
  unsigned int sign = (u >> 24) & 0x80u;
  int e8 = (int)((u >> 23) & 0xFF) - 127 + 7;
  if (e8 >= 1) {
    unsigned int man = u & 0x7FFFFFu;
    unsigned int m = man >> 20;
    unsigned int rem = man & 0xFFFFFu;
    if (rem > 0x80000u || (rem == 0x80000u && (m & 1u))) ++m;
    if (m == 8u) { m = 0u; ++e8; }
    return (u8)(sign | ((unsigned)e8 << 3) | m);
  } else {
    float af = __uint_as_float(u & 0x7FFFFFFFu);
    int q = (int)rintf(af * 512.0f);          // subnormal quantum 2^-9
    if (q >= 8) return (u8)(sign | (1u << 3)); // rounds up to min normal
    return (u8)(sign | (unsigned)q);
  }
}

// async global->LDS, 16B/lane (global_load_lds_dwordx4); LDS dest must be
// wave-uniform base + lane*16 — chunk mapping guarantees that.
__device__ __forceinline__ void async16(const void* g, void* l) {
  auto gp = reinterpret_cast<const __attribute__((address_space(1))) unsigned int*>(
      reinterpret_cast<uintptr_t>(g));
  auto lp = reinterpret_cast<__attribute__((address_space(3))) unsigned int*>(
      reinterpret_cast<uintptr_t>(l));
  __builtin_amdgcn_global_load_lds(gp, lp, 16, 0, 0);
}

// ---- adj -> Ms bf16, Ms fp8 (x2^20), Ms^T fp8 (x2^20), fused -------------
extern "C" __global__ void __launch_bounds__(256) k_split_tr(
    const float* __restrict__ src, u16* __restrict__ Z16,
    u8* __restrict__ Z8, u8* __restrict__ Zt8, float s, float s8) {
  __shared__ float tile[64][65];
  const int tx = threadIdx.x & 63;
  const int ty = threadIdx.x >> 6;
  const int r0 = blockIdx.y * 64, c0 = blockIdx.x * 64;
  for (int r = ty; r < 64; r += 4) {
    size_t g = (size_t)(r0 + r) * NN + (c0 + tx);
    float v = s * src[g];
    tile[r][tx] = v;
    Z16[g] = f2bf(v);
    Z8[g] = f2e4m3(v * s8);
  }
  __syncthreads();
  for (int r = ty; r < 64; r += 4)
    Zt8[(size_t)(c0 + r) * NN + (r0 + tx)] = f2e4m3(tile[tx][r] * s8);
}

// ---- FP8 GEMM: vc = accScale*(A8*Bt8^T) + e1*X + e2*Y --------------------
// writes C16 = bf16(vc); if C8: C8 = fp8(vc*sC8), C8t = fp8(t*sT8)^T;
// if Ct16 (last): Ct16 = bf16(t)^T, where t = tv*acc*accScale + tx*X + ty*Y.
// 128x128 tile, BK=128, 4 waves x (4x4 of 16x16x128 f8f6f4, unit scales).
extern "C" __global__ void __launch_bounds__(256, 3) k_gemm8(
    const u8* __restrict__ A8, const u8* __restrict__ Bt8,
    u16* __restrict__ C16, u8* __restrict__ C8, u8* __restrict__ C8t,
    u16* __restrict__ Ct16,
    const u16* __restrict__ X16, const u16* __restrict__ Y16,
    float accScale, float e1, float e2,
    float tv, float tx, float ty, float sC8, float sT8) {
  // union: staging sA|sB (32KB) / fp8 transpose tile (18KB) / bf16 tile (35KB)
  __shared__ alignas(16) u16 smem16[128 * TP];
  u8* smem8 = (u8*)smem16;
  u8* sA = smem8;
  u8* sB = smem8 + 16384;

  const int tid  = threadIdx.x;
  const int lane = tid & 63;
  const int wave = tid >> 6;
  const int wr = wave >> 1, wc = wave & 1;
  const int quad = lane >> 4;
  const int lrow = lane & 15;

  // grouped swizzle: bands of 8x8 tiles for L2/L3 panel locality
  const int bid = blockIdx.x;
  const int group = bid >> 6, inb = bid & 63;
  const int m0 = ((group & 3) * 8 + (inb & 7)) * BM;
  const int n0 = ((group >> 2) * 8 + (inb >> 3)) * BN;

  f32x4 acc[4][4];
#pragma unroll
  for (int i = 0; i < 4; ++i)
#pragma unroll
    for (int j = 0; j < 4; ++j) acc[i][j] = (f32x4){0.f, 0.f, 0.f, 0.f};

  // staging: plane tile 128x128 fp8 = 16KB = 1024 chunks of 16B; 4/thread.
  // XOR swizzle: chunk q holds global (row=q>>3, col16=((q&7)^(row&7))*16).
  unsigned int ga[4], gb[4];
  int lo[4];
#pragma unroll
  for (int c = 0; c < 4; ++c) {
    int q = tid + c * 256;
    int row = q >> 3;
    int col = ((q & 7) ^ (row & 7)) * 16;
    ga[c] = (unsigned int)(m0 + row) * NN + col;
    gb[c] = (unsigned int)(n0 + row) * NN + col;
    lo[c] = q * 16;
  }

  // fragment chunk column (post-swizzle); rows r have r&7 == lrow&7
  const int c0f = (quad * 2) ^ (lrow & 7);   // lower 16B of the 32B k-group

  for (int k = 0; k < NN; k += 128) {
#pragma unroll
    for (int c = 0; c < 4; ++c) {
      async16(A8 + ga[c] + k, sA + lo[c]);
      async16(Bt8 + gb[c] + k, sB + lo[c]);
    }
    asm volatile("s_waitcnt vmcnt(0)" ::: "memory");
    __syncthreads();

    v8i a8[4], b8[4];
#pragma unroll
    for (int mi = 0; mi < 4; ++mi) {
      const int r = wr * 64 + mi * 16 + lrow;
      const uint4 q0 = *(const uint4*)&sA[r * 128 + c0f * 16];
      const uint4 q1 = *(const uint4*)&sA[r * 128 + (c0f ^ 1) * 16];
      a8[mi] = (v8i){(int)q0.x, (int)q0.y, (int)q0.z, (int)q0.w,
                     (int)q1.x, (int)q1.y, (int)q1.z, (int)q1.w};
    }
#pragma unroll
    for (int ni = 0; ni < 4; ++ni) {
      const int r = wc * 64 + ni * 16 + lrow;
      const uint4 q0 = *(const uint4*)&sB[r * 128 + c0f * 16];
      const uint4 q1 = *(const uint4*)&sB[r * 128 + (c0f ^ 1) * 16];
      b8[ni] = (v8i){(int)q0.x, (int)q0.y, (int)q0.z, (int)q0.w,
                     (int)q1.x, (int)q1.y, (int)q1.z, (int)q1.w};
    }
#pragma unroll
    for (int mi = 0; mi < 4; ++mi)
#pragma unroll
      for (int ni = 0; ni < 4; ++ni)
        acc[mi][ni] = __builtin_amdgcn_mfma_scale_f32_16x16x128_f8f6f4(
            a8[mi], b8[ni], acc[mi][ni], 0, 0, 0, 0x7F, 0, 0x7F);
    __syncthreads();   // also guards smem reuse by the epilogue on last iter
  }

  const bool hasX = (X16 != nullptr);
  const bool hasY = (Y16 != nullptr);
  const bool last = (Ct16 != nullptr);
#pragma unroll
  for (int mi = 0; mi < 4; ++mi)
#pragma unroll
    for (int ni = 0; ni < 4; ++ni) {
      const int lm = wr * 64 + mi * 16 + quad * 4;
      const int ln = wc * 64 + ni * 16 + lrow;
      const int gn = n0 + ln;
#pragma unroll
      for (int r = 0; r < 4; ++r) {
        const int gm = m0 + lm + r;
        const size_t g = (size_t)gm * NN + gn;
        const float vraw = acc[mi][ni][r] * accScale;
        const float xv = hasX ? bf2f(X16[g]) : 0.f;
        const float yv = hasY ? bf2f(Y16[g]) : 0.f;
        const float vc = vraw + e1 * xv + e2 * yv;
        const float t = tv * vraw + tx * xv + ty * yv;
        C16[g] = f2bf(vc);
        if (last) {
          smem16[ln * TP + lm + r] = f2bf(t);
        } else {
          C8[g] = f2e4m3(vc * sC8);
          smem8[ln * TP8 + lm + r] = f2e4m3(t * sT8);
        }
      }
    }
  __syncthreads();

  if (last) {
    // coalesced bf16 Ct: wave covers local-n rows [wave*32, wave*32+32)
    const int sr = lane >> 4;
    const int c16 = lane & 15;
#pragma unroll
    for (int it = 0; it < 8; ++it) {
      const int row = wave * 32 + it * 4 + sr;
      const u16* srcp = &smem16[row * TP + c16 * 8];
      uint2 lo8 = *(const uint2*)(srcp);
      uint2 hi8 = *(const uint2*)(srcp + 4);
      uint4 q; q.x = lo8.x; q.y = lo8.y; q.z = hi8.x; q.w = hi8.y;
      *(uint4*)(Ct16 + (size_t)(n0 + row) * NN + m0 + c16 * 8) = q;
    }
  } else {
    // coalesced fp8 C8t: 1024 chunks of 16B, 4/thread
#pragma unroll
    for (int cc = 0; cc < 4; ++cc) {
      const int qq = tid + cc * 256;
      const int row = qq >> 3, p = qq & 7;
      uint4 v = *(const uint4*)&smem8[row * TP8 + p * 16];
      *(uint4*)&C8t[(size_t)(n0 + row) * NN + m0 + p * 16] = v;
    }
  }
}

// ---- per-row 16th-largest of heat = (Y2 + I) (exact, iterative argmax) ---
extern "C" __global__ void __launch_bounds__(256) k_topk(
    const u16* __restrict__ Hh, float* __restrict__ thr) {
  __shared__ float vals[NN];
  __shared__ float wv[4];
  __shared__ int wi[4];
  const int row = blockIdx.x;
  const int tid = threadIdx.x;
  for (int j = tid; j < NN; j += 256) {
    size_t g = (size_t)row * NN + j;
    vals[j] = bf2f(Hh[g]) + ((j == row) ? 1.f : 0.f);
  }
  __syncthreads();
  for (int it = 0; it < 16; ++it) {
    float best = -3.0e38f;
    int bidx = 1 << 30;
    for (int j = tid; j < NN; j += 256) {
      float v = vals[j];
      if (v > best) { best = v; bidx = j; }
    }
#pragma unroll
    for (int off = 32; off > 0; off >>= 1) {
      float ov = __shfl_down(best, off);
      int oi = __shfl_down(bidx, off);
      if (ov > best || (ov == best && oi < bidx)) { best = ov; bidx = oi; }
    }
    if ((tid & 63) == 0) { wv[tid >> 6] = best; wi[tid >> 6] = bidx; }
    __syncthreads();
    if (tid == 0) {
      for (int w = 1; w < 4; ++w)
        if (wv[w] > wv[0] || (wv[w] == wv[0] && wi[w] < wi[0])) {
          wv[0] = wv[w]; wi[0] = wi[w];
        }
      vals[wi[0]] = -3.0e38f;      // mark taken (handles duplicates exactly)
      if (it == 15) thr[row] = wv[0];
    }
    __syncthreads();
  }
}

// ---- mask + symmetrize + add I + row-normalize (heat = Y2 + I) -----------
extern "C" __global__ void __launch_bounds__(256) k_final(
    const u16* __restrict__ Hh,    // Y2 rows
    const u16* __restrict__ Th,    // Y2^T rows
    const float* __restrict__ thr, float* __restrict__ out) {
  __shared__ float v[NN];
  __shared__ float wsum[4];
  const int row = blockIdx.x;
  const int tid = threadIdx.x;
  const float ti = thr[row];
  float s = 0.f;
  for (int j = tid; j < NN; j += 256) {
    size_t g = (size_t)row * NN + j;
    const float ind = (j == row) ? 1.f : 0.f;
    float hij = bf2f(Hh[g]) + ind;
    float hji = bf2f(Th[g]) + ind;
    float val = (hij >= ti || hji >= thr[j]) ? 0.5f * (hij + hji) : 0.f;
    val += ind;                                   // + eye after masking
    v[j] = val;
    s += val;
  }
#pragma unroll
  for (int off = 32; off > 0; off >>= 1) s += __shfl_down(s, off);
  if ((tid & 63) == 0) wsum[tid >> 6] = s;
  __syncthreads();
  const float inv = 1.f / (wsum[0] + wsum[1] + wsum[2] + wsum[3]);
  for (int j = tid; j < NN; j += 256)
    out[(size_t)row * NN + j] = v[j] * inv;
}

extern "C" void kernel_launch(void* const* d_in, const int* in_sizes, int n_in,
                              void* d_out, int out_size, void* d_ws, size_t ws_size,
                              hipStream_t stream) {
  const float* adj = (const float*)d_in[0];
  char* ws = (char*)d_ws;
  const size_t U = (size_t)NN * NN;             // 16 MiB unit (fp8 plane size)
  // bf16 plane = 2 units, fp8 plane = 1 unit. ws >= 8 units + 16 KB.
  u16* Ms16  = (u16*)(ws);                      // u0-1 (bf16)
  u8*  MsF   = (u8*)(ws + 2 * U);               // u2
  u8*  MstF  = (u8*)(ws + 3 * U);               // u3
  u8*  M2F   = (u8*)(ws + 4 * U);               // u4
  u8*  GtF   = (u8*)(ws + 5 * U);               // u5
  u8*  Y0F   = (u8*)(ws + 6 * U);               // u6
  u8*  Y0tF  = (u8*)(ws + 7 * U);               // u7
  u16* Y1_16 = (u16*)(ws);                      // u0-1 (Ms16 dead after G2)
  u8*  Y1F   = (u8*)(ws + 2 * U);               // u2 (MsF dead)
  u8*  Y1tF  = (u8*)(ws + 3 * U);               // u3 (MstF dead)
  u16* Y2_16 = (u16*)(ws + 4 * U);              // u4-5 (M2F/GtF dead)
  u16* Y2t16 = (u16*)(ws + 6 * U);              // u6-7 (Y0F/Y0tF dead)
  float* thr = (float*)(ws + 8 * U);
  u16* M2_16 = (u16*)d_out;                     // d_out lower 32MB, scratch
  u16* Y0_16 = (u16*)((char*)d_out + 2 * U);    // d_out upper 32MB, scratch
  float* out = (float*)d_out;

  const dim3 b(256);
  const u16* n16 = nullptr;
  u8* n8 = nullptr;

  // 1) Ms = -5/4*adj: bf16 -> Ms16, fp8*2^20 -> MsF, (Ms^T)*2^20 -> MstF
  k_split_tr<<<dim3(64, 64), b, 0, stream>>>(adj, Ms16, MsF, MstF,
                                             -1.25f, 0x1p20f);
  // 2) M2 = Ms*Ms; C=M2 (bf16 + fp8*2^20); Ct = G^T = (Ms/6 + M2/24)^T fp8*2^22
  k_gemm8<<<dim3(1024), b, 0, stream>>>(MsF, MstF, M2_16, M2F, GtF, (u16*)nullptr,
                                        Ms16, n16,
                                        0x1p-40f, 0.f, 0.f,
                                        1.f / 24.f, 1.f / 6.f, 0.f,
                                        0x1p20f, 0x1p22f);
  // 3) Y0 = M2*G + Ms + M2/2; C=Y0 (bf16 + fp8*2^19); Ct = Y0^T fp8*2^19
  k_gemm8<<<dim3(1024), b, 0, stream>>>(M2F, GtF, Y0_16, Y0F, Y0tF, (u16*)nullptr,
                                        Ms16, M2_16,
                                        0x1p-42f, 1.f, 0.5f,
                                        1.f, 1.f, 0.5f,
                                        0x1p19f, 0x1p19f);
  // 4) Y1 = Y0*Y0 + 2*Y0; C=Y1 (bf16 + fp8*2^17); Ct = Y1^T fp8*2^17
  k_gemm8<<<dim3(1024), b, 0, stream>>>(Y0F, Y0tF, Y1_16, Y1F, Y1tF, (u16*)nullptr,
                                        Y0_16, n16,
                                        0x1p-38f, 2.f, 0.f,
                                        1.f, 2.f, 0.f,
                                        0x1p17f, 0x1p17f);
  // 5) Y2 = Y1*Y1 + 2*Y1; C=Y2 bf16; Ct = Y2^T bf16 (terminal, no fp8)
  k_gemm8<<<dim3(1024), b, 0, stream>>>(Y1F, Y1tF, Y2_16, n8, n8, Y2t16,
                                        Y1_16, n16,
                                        0x1p-34f, 2.f, 0.f,
                                        1.f, 2.f, 0.f,
                                        1.f, 1.f);
  // 6) per-row 16th-largest of heat -> thr
  k_topk<<<dim3(NN), b, 0, stream>>>(Y2_16, thr);
  // 7) mask/sym/normalize -> out (overwrites d_out; M2_16/Y0_16 dead)
  k_final<<<dim3(NN), b, 0, stream>>>(Y2_16, Y2t16, thr, out);
}